// Round 5
// baseline (327.702 us; speedup 1.0000x reference)
//
#include <hip/hip_runtime.h>

// 9x9 box filter (r=4), reflect padding, 24 planes of 2048x2048 f32.
// R5: back to R2's register-ring (1x read traffic), but with a fully
// BRANCHLESS loop body so the compiler can software-pipeline global loads
// across row-steps (the 3-way divergent load16 branch was blocking load
// hoisting -> every wave ate full memory latency per row; VALUBusy was 9%).
// All threads load 4x float4 from clamp(c0-4, 0, W-16) (in-bounds, aligned);
// t==0 / t==255 remap lanes with compile-time permutations via data selects.

constexpr int H   = 2048;
constexpr int W   = 2048;
constexpr int R   = 4;             // radius (reference uses r=4)
constexpr int RH  = 32;            // output rows per block
constexpr int TPB = 256;           // one full row: 256 threads * 8 cols

typedef float f32x4 __attribute__((ext_vector_type(4)));

__device__ __forceinline__ int reflect_row(int r) {
  r = (r < 0) ? -r : r;
  return (r >= H) ? (2 * H - 2 - r) : r;
}

// Lane remaps for the clamped edge loads (compile-time i only).
// t==0:   loaded L[i] = row[i];        need v[i] = row[reflect(i-4)]
// t==255: loaded L[i] = row[2032+i];   need v[i] = row[reflect(2036+i)]
constexpr int perm0(int i) { return i < 4 ? 4 - i : i - 4; }
constexpr int permN(int i) { return i < 12 ? 4 + i : 26 - i; } // 12..15 -> 14,13,12,11

template <int P, bool STORE>
__device__ __forceinline__ void bf_step(
    int s, int r0, bool e0, bool eN, int off, int c0,
    const float* __restrict__ px, float* __restrict__ po,
    float (&hbuf)[9][8], float (&vsum)[8]) {
  const int lr = reflect_row(r0 - R + s);
  const float* __restrict__ base = px + (size_t)lr * W + off;

  float L[16];
  *(f32x4*)(L + 0)  = *(const f32x4*)(base + 0);
  *(f32x4*)(L + 4)  = *(const f32x4*)(base + 4);
  *(f32x4*)(L + 8)  = *(const f32x4*)(base + 8);
  *(f32x4*)(L + 12) = *(const f32x4*)(base + 12);

  // v[i] = row[c0-4+i] with column reflect; pure data selects, no branches
  float v[16];
#pragma unroll
  for (int i = 0; i < 16; ++i) {
    float vi = L[i];
    vi = e0 ? L[perm0(i)] : vi;
    vi = eN ? L[permN(i)] : vi;
    v[i] = vi;
  }

  // horizontal sliding 9-sums: h[j] = sum(v[j..j+8])
  float h[8];
  h[0] = ((v[0] + v[1]) + (v[2] + v[3])) +
         ((v[4] + v[5]) + (v[6] + v[7])) + v[8];
#pragma unroll
  for (int j = 1; j < 8; ++j) h[j] = h[j - 1] + v[j + 8] - v[j - 1];

  // vertical running 9-sum via ring buffer (phase P is compile-time)
#pragma unroll
  for (int j = 0; j < 8; ++j) {
    vsum[j]    += h[j] - hbuf[P][j];
    hbuf[P][j]  = h[j];
  }

  if (STORE) {
    const float inv81 = 1.0f / 81.0f;
    float* o = po + (size_t)(r0 + s - 2 * R) * W + c0;
    f32x4 o0 = {vsum[0] * inv81, vsum[1] * inv81,
                vsum[2] * inv81, vsum[3] * inv81};
    f32x4 o1 = {vsum[4] * inv81, vsum[5] * inv81,
                vsum[6] * inv81, vsum[7] * inv81};
    __builtin_nontemporal_store(o0, (f32x4*)(o + 0));
    __builtin_nontemporal_store(o1, (f32x4*)(o + 4));
  }
}

__global__ __launch_bounds__(TPB) void BoxFilter_kernel(
    const float* __restrict__ x, float* __restrict__ out) {
  const int t     = threadIdx.x;
  const int bid   = blockIdx.x;
  const int plane = bid >> 6;        // H/RH == 64 chunks per plane
  const int chunk = bid & 63;
  const int r0    = chunk * RH;
  const float* __restrict__ px = x   + (size_t)plane * H * W;
  float*       __restrict__ po = out + (size_t)plane * H * W;
  const int c0 = t << 3;             // first output column of this thread

  int off = c0 - R;                  // clamped, in-bounds, 16B-aligned
  off = off < 0 ? 0 : off;
  off = off > W - 16 ? W - 16 : off;
  const bool e0 = (t == 0);
  const bool eN = (t == TPB - 1);

  float hbuf[9][8];
  float vsum[8];
#pragma unroll
  for (int j = 0; j < 8; ++j) vsum[j] = 0.0f;
#pragma unroll
  for (int p = 0; p < 9; ++p)
#pragma unroll
    for (int j = 0; j < 8; ++j) hbuf[p][j] = 0.0f;

  // warmup: s = 0..7 (phases 0..7), no store
  bf_step<0, false>(0, r0, e0, eN, off, c0, px, po, hbuf, vsum);
  bf_step<1, false>(1, r0, e0, eN, off, c0, px, po, hbuf, vsum);
  bf_step<2, false>(2, r0, e0, eN, off, c0, px, po, hbuf, vsum);
  bf_step<3, false>(3, r0, e0, eN, off, c0, px, po, hbuf, vsum);
  bf_step<4, false>(4, r0, e0, eN, off, c0, px, po, hbuf, vsum);
  bf_step<5, false>(5, r0, e0, eN, off, c0, px, po, hbuf, vsum);
  bf_step<6, false>(6, r0, e0, eN, off, c0, px, po, hbuf, vsum);
  bf_step<7, false>(7, r0, e0, eN, off, c0, px, po, hbuf, vsum);
  // s = 8 (phase 8): first output row
  bf_step<8, true>(8, r0, e0, eN, off, c0, px, po, hbuf, vsum);

  // steady: s = 9..35, three groups of 9 (phases 0..8), kept rolled
#pragma unroll 1
  for (int s0 = 9; s0 <= 27; s0 += 9) {
    bf_step<0, true>(s0 + 0, r0, e0, eN, off, c0, px, po, hbuf, vsum);
    bf_step<1, true>(s0 + 1, r0, e0, eN, off, c0, px, po, hbuf, vsum);
    bf_step<2, true>(s0 + 2, r0, e0, eN, off, c0, px, po, hbuf, vsum);
    bf_step<3, true>(s0 + 3, r0, e0, eN, off, c0, px, po, hbuf, vsum);
    bf_step<4, true>(s0 + 4, r0, e0, eN, off, c0, px, po, hbuf, vsum);
    bf_step<5, true>(s0 + 5, r0, e0, eN, off, c0, px, po, hbuf, vsum);
    bf_step<6, true>(s0 + 6, r0, e0, eN, off, c0, px, po, hbuf, vsum);
    bf_step<7, true>(s0 + 7, r0, e0, eN, off, c0, px, po, hbuf, vsum);
    bf_step<8, true>(s0 + 8, r0, e0, eN, off, c0, px, po, hbuf, vsum);
  }
  // tail: s = 36..39 (phases 0..3)
  bf_step<0, true>(36, r0, e0, eN, off, c0, px, po, hbuf, vsum);
  bf_step<1, true>(37, r0, e0, eN, off, c0, px, po, hbuf, vsum);
  bf_step<2, true>(38, r0, e0, eN, off, c0, px, po, hbuf, vsum);
  bf_step<3, true>(39, r0, e0, eN, off, c0, px, po, hbuf, vsum);
}

extern "C" void kernel_launch(void* const* d_in, const int* in_sizes, int n_in,
                              void* d_out, int out_size, void* d_ws, size_t ws_size,
                              hipStream_t stream) {
  const float* x   = (const float*)d_in[0];
  float*       out = (float*)d_out;
  const int planes = out_size / (H * W);        // 8*3 = 24
  dim3 grid(planes * (H / RH));                 // 24 * 64 = 1536 blocks
  dim3 block(TPB);
  hipLaunchKernelGGL(BoxFilter_kernel, grid, block, 0, stream, x, out);
}

// Round 6
// 173.429 us; speedup vs baseline: 1.8895x; 1.8895x over previous
//
#include <hip/hip_runtime.h>

// 9x9 box filter (r=4), reflect padding, 24 planes of 2048x2048 f32.
// R6: 4 cols/thread -> (a) lane-contiguous full-density float4 loads
// (16B lane stride = perfect 1KB bursts; the 8-col version had 32B stride,
// half-density), (b) hbuf ring halves to 9x4 -> ~80 VGPR -> 6 waves/SIMD,
// (c) ZERO branches / selects in the row loop: column reflect is done by a
// tiny edge_fix kernel that exactly recomputes the 8 boundary columns per
// row (main kernel stores clamped garbage there; same-stream ordering).
// SROA rule from R5: no vector-pointer punning of local arrays -- load into
// float4 temps, use members only.

constexpr int H   = 2048;
constexpr int W   = 2048;
constexpr int R   = 4;             // radius (reference uses r=4)
constexpr int RH  = 32;            // output rows per block
constexpr int TPB = 256;
constexpr int CPT = 4;             // cols per thread
constexpr int BCOLS = TPB * CPT;   // 1024 cols per block (2 blocks per row)

typedef float f32x4 __attribute__((ext_vector_type(4)));

__device__ __forceinline__ int reflect_row(int r) {
  r = (r < 0) ? -r : r;
  return (r >= H) ? (2 * H - 2 - r) : r;
}

template <int P, bool STORE>
__device__ __forceinline__ void bf_step(
    int s, int r0, int off, int c0,
    const float* __restrict__ px, float* __restrict__ po,
    float (&hbuf)[9][CPT], float (&vsum)[CPT]) {
  const int lr = reflect_row(r0 - R + s);
  const float* __restrict__ rowp = px + (size_t)lr * W;

  // 12 floats covering windows of 4 outputs: rowp[off .. off+11]
  const float4 A = *(const float4*)(rowp + off);      // v0..v3
  const float4 B = *(const float4*)(rowp + off + 4);  // v4..v7
  const float4 C = *(const float4*)(rowp + off + 8);  // v8..v11

  float h0 = ((A.x + A.y) + (A.z + A.w)) +
             ((B.x + B.y) + (B.z + B.w)) + C.x;
  float h1 = h0 + C.y - A.x;
  float h2 = h1 + C.z - A.y;
  float h3 = h2 + C.w - A.z;

  vsum[0] += h0 - hbuf[P][0]; hbuf[P][0] = h0;
  vsum[1] += h1 - hbuf[P][1]; hbuf[P][1] = h1;
  vsum[2] += h2 - hbuf[P][2]; hbuf[P][2] = h2;
  vsum[3] += h3 - hbuf[P][3]; hbuf[P][3] = h3;

  if (STORE) {
    const float inv81 = 1.0f / 81.0f;
    float* o = po + (size_t)(r0 + s - 2 * R) * W + c0;
    f32x4 ov = {vsum[0] * inv81, vsum[1] * inv81,
                vsum[2] * inv81, vsum[3] * inv81};
    __builtin_nontemporal_store(ov, (f32x4*)o);
  }
}

__global__ __launch_bounds__(TPB, 5) void BoxFilter_kernel(
    const float* __restrict__ x, float* __restrict__ out) {
  const int t    = threadIdx.x;
  const int bid  = blockIdx.x;
  const int plane = bid >> 7;          // 64 chunks * 2 halves = 128 per plane
  const int rem   = bid & 127;
  const int chunk = rem >> 1;
  const int half  = rem & 1;
  const int r0    = chunk * RH;
  const int cb    = half * BCOLS;
  const float* __restrict__ px = x   + (size_t)plane * H * W;
  float*       __restrict__ po = out + (size_t)plane * H * W;

  const int c0 = cb + t * CPT;         // first output col (16B aligned)
  int off = c0 - R;                    // clamped load base (16B aligned)
  off = off < 0 ? 0 : off;
  off = off > W - 12 ? W - 12 : off;   // W-12 = 2036, 16B aligned

  float hbuf[9][CPT];
  float vsum[CPT];
#pragma unroll
  for (int j = 0; j < CPT; ++j) vsum[j] = 0.0f;
#pragma unroll
  for (int p = 0; p < 9; ++p)
#pragma unroll
    for (int j = 0; j < CPT; ++j) hbuf[p][j] = 0.0f;

  // warmup: s = 0..7 (phases 0..7), no store
  bf_step<0, false>(0, r0, off, c0, px, po, hbuf, vsum);
  bf_step<1, false>(1, r0, off, c0, px, po, hbuf, vsum);
  bf_step<2, false>(2, r0, off, c0, px, po, hbuf, vsum);
  bf_step<3, false>(3, r0, off, c0, px, po, hbuf, vsum);
  bf_step<4, false>(4, r0, off, c0, px, po, hbuf, vsum);
  bf_step<5, false>(5, r0, off, c0, px, po, hbuf, vsum);
  bf_step<6, false>(6, r0, off, c0, px, po, hbuf, vsum);
  bf_step<7, false>(7, r0, off, c0, px, po, hbuf, vsum);
  // s = 8 (phase 8): first output row
  bf_step<8, true>(8, r0, off, c0, px, po, hbuf, vsum);

  // steady: s = 9..35, three groups of 9 (phases 0..8)
#pragma unroll 1
  for (int s0 = 9; s0 <= 27; s0 += 9) {
    bf_step<0, true>(s0 + 0, r0, off, c0, px, po, hbuf, vsum);
    bf_step<1, true>(s0 + 1, r0, off, c0, px, po, hbuf, vsum);
    bf_step<2, true>(s0 + 2, r0, off, c0, px, po, hbuf, vsum);
    bf_step<3, true>(s0 + 3, r0, off, c0, px, po, hbuf, vsum);
    bf_step<4, true>(s0 + 4, r0, off, c0, px, po, hbuf, vsum);
    bf_step<5, true>(s0 + 5, r0, off, c0, px, po, hbuf, vsum);
    bf_step<6, true>(s0 + 6, r0, off, c0, px, po, hbuf, vsum);
    bf_step<7, true>(s0 + 7, r0, off, c0, px, po, hbuf, vsum);
    bf_step<8, true>(s0 + 8, r0, off, c0, px, po, hbuf, vsum);
  }
  // tail: s = 36..39 (phases 0..3)
  bf_step<0, true>(36, r0, off, c0, px, po, hbuf, vsum);
  bf_step<1, true>(37, r0, off, c0, px, po, hbuf, vsum);
  bf_step<2, true>(38, r0, off, c0, px, po, hbuf, vsum);
  bf_step<3, true>(39, r0, off, c0, px, po, hbuf, vsum);
}

// Exact recompute of the 8 boundary columns (0..3, 2044..2047) of every row,
// where the main kernel's clamped loads produced garbage. One thread per row.
__global__ __launch_bounds__(TPB) void edge_fix(
    const float* __restrict__ x, float* __restrict__ out) {
  const int idx = blockIdx.x * blockDim.x + threadIdx.x; // 0 .. 24*2048-1
  const int plane = idx >> 11;
  const int r     = idx & (H - 1);
  const float* __restrict__ px = x   + (size_t)plane * H * W;
  float*       __restrict__ po = out + (size_t)plane * H * W;

  float accL[4] = {0.f, 0.f, 0.f, 0.f};
  float accR[4] = {0.f, 0.f, 0.f, 0.f};

#pragma unroll
  for (int dr = -R; dr <= R; ++dr) {
    const int rr = reflect_row(r + dr);
    const float* __restrict__ rowp = px + (size_t)rr * W;
    float l[9], m[9];
#pragma unroll
    for (int i = 0; i < 9; ++i) l[i] = rowp[i];            // cols 0..8
#pragma unroll
    for (int i = 0; i < 9; ++i) m[i] = rowp[W - 9 + i];    // cols 2039..2047
#pragma unroll
    for (int c = 0; c < 4; ++c) {
#pragma unroll
      for (int k = -R; k <= R; ++k) {
        int j = c + k; j = (j < 0) ? -j : j;               // col reflect left
        accL[c] += l[j];
        int rc = (W - 4 + c) + k;                          // 2044+c+k
        rc = (rc >= W) ? (2 * W - 2 - rc) : rc;            // col reflect right
        accR[c] += m[rc - (W - 9)];
      }
    }
  }

  const float inv81 = 1.0f / 81.0f;
  float* oL = po + (size_t)r * W;
  float* oR = po + (size_t)r * W + (W - 4);
  f32x4 vL = {accL[0] * inv81, accL[1] * inv81, accL[2] * inv81, accL[3] * inv81};
  f32x4 vR = {accR[0] * inv81, accR[1] * inv81, accR[2] * inv81, accR[3] * inv81};
  *(f32x4*)oL = vL;
  *(f32x4*)oR = vR;
}

extern "C" void kernel_launch(void* const* d_in, const int* in_sizes, int n_in,
                              void* d_out, int out_size, void* d_ws, size_t ws_size,
                              hipStream_t stream) {
  const float* x   = (const float*)d_in[0];
  float*       out = (float*)d_out;
  const int planes = out_size / (H * W);              // 8*3 = 24
  dim3 grid(planes * (H / RH) * 2);                   // 24 * 64 * 2 = 3072
  dim3 block(TPB);
  hipLaunchKernelGGL(BoxFilter_kernel, grid, block, 0, stream, x, out);
  dim3 fgrid(planes * H / TPB);                       // 24*2048/256 = 192
  hipLaunchKernelGGL(edge_fix, fgrid, block, 0, stream, x, out);
}